// Round 7
// baseline (260.957 us; speedup 1.0000x reference)
//
#include <hip/hip_runtime.h>
#include <hip/hip_bf16.h>
#include <stdint.h>

#define HWsz 3136
#define Hh   56
#define Cc   384
#define NHEADS 6
#define NB   8

typedef __attribute__((ext_vector_type(8))) short short8;
typedef __attribute__((ext_vector_type(4))) short short4v;
typedef __attribute__((ext_vector_type(4))) float f32x4;

static __device__ __forceinline__ short f2bf(float f) {
  __hip_bfloat16 h = __float2bfloat16(f);
  return (short)__builtin_bit_cast(unsigned short, h);
}

// ---------------- weight conversion (fold q-scale 0.125 into first 384 rows of w_qkv)
__global__ void prep_weights(const float* __restrict__ wq, const float* __restrict__ wp,
                             short* __restrict__ wqb, short* __restrict__ wpb) {
  int stride = gridDim.x * blockDim.x;
  for (int i = blockIdx.x * blockDim.x + threadIdx.x; i < 3 * Cc * Cc; i += stride) {
    float v = wq[i];
    if (i < Cc * Cc) v *= 0.125f;
    wqb[i] = f2bf(v);
  }
  for (int i = blockIdx.x * blockDim.x + threadIdx.x; i < Cc * Cc; i += stride)
    wpb[i] = f2bf(wp[i]);
}

// ---------------- bf16 MFMA GEMM: D[o,p] = sum_k A[o][k]*B[k][p-ish], K=384
// 1-D grid, b = blockIdx.x & 7  -> XCD b owns batch b (HW round-robins slot->XCD mod 8).
// idx = blockIdx.x >> 3; om fast -> B-panel stays L2-resident across om-blocks.
// MODE 0: B = x f32 [b][c][3136] (transpose fused in staging);
//         o<768 -> qk[b][p][768] bf16; o>=768 -> vtp[b][ch][62][64] padded image
// MODE 1: B = attn_out bf16 [b][p][384] rows; out f32 [b][o][3136]
template<int MODE>
__global__ __launch_bounds__(256) void gemm_bf16(
    const short* __restrict__ A, const void* __restrict__ Bsrc,
    const float* __restrict__ bias, void* __restrict__ o1, void* __restrict__ o2)
{
  constexpr int K = Cc;
  constexpr int NOM = (MODE == 0 ? 9 : 3);
  const int b   = blockIdx.x & 7;
  const int idx = blockIdx.x >> 3;
  const int om0 = (idx % NOM) * 128;
  const int pn0 = (idx / NOM) * 128;
  __shared__ short lA[128 * 40];
  __shared__ short lB[128 * 40];
  const int t    = threadIdx.x;
  const int lane = t & 63;
  const int wave = t >> 6;
  const int wm = (wave >> 1) * 64;
  const int wn = (wave & 1) * 64;
  f32x4 acc[4][4] = {};
  const int fr = lane & 15;
  const int fo = lane >> 4;
  // A staging map (both modes)
  const int sr = t >> 2;
  const int sk = (t & 3) * 8;
  // MODE0 B staging map: 16 c-pairs x 16 p-groups of 8
  const int pg = t & 15, cpair = t >> 4;
  const int pbase = pn0 + pg * 8;
  const int po0 = pbase     > HWsz - 4 ? HWsz - 4 : pbase;
  const int po1 = pbase + 4 > HWsz - 4 ? HWsz - 4 : pbase + 4;
  const float* Bx = (const float*)Bsrc + (size_t)b * Cc * HWsz;
  // MODE1 B staging map
  const short* Bb = (const short*)Bsrc + (size_t)b * HWsz * K;
  int pr0 = pn0 + sr;      if (pr0 > HWsz - 1) pr0 = HWsz - 1;
  int pr1 = pn0 + sr + 64; if (pr1 > HWsz - 1) pr1 = HWsz - 1;

  for (int k0 = 0; k0 < K; k0 += 32) {
    short8 a0 = *(const short8*)(A + (size_t)(om0 + sr) * K + k0 + sk);
    short8 a1 = *(const short8*)(A + (size_t)(om0 + sr + 64) * K + k0 + sk);
    f32x4 x00, x01, x10, x11; short8 b0, b1;
    if (MODE == 0) {
      const float* r0 = Bx + (size_t)(k0 + 2 * cpair) * HWsz;
      x00 = *(const f32x4*)(r0 + po0);
      x01 = *(const f32x4*)(r0 + po1);
      x10 = *(const f32x4*)(r0 + HWsz + po0);
      x11 = *(const f32x4*)(r0 + HWsz + po1);
    } else {
      b0 = *(const short8*)(Bb + (size_t)pr0 * K + k0 + sk);
      b1 = *(const short8*)(Bb + (size_t)pr1 * K + k0 + sk);
    }
    __syncthreads();
    *(short8*)(lA + sr * 40 + sk) = a0;
    *(short8*)(lA + (sr + 64) * 40 + sk) = a1;
    if (MODE == 0) {
      uint32_t* lB32 = (uint32_t*)lB;
#pragma unroll
      for (int qq = 0; qq < 8; ++qq) {
        float va = (qq < 4) ? x00[qq] : x01[qq - 4];
        float vb = (qq < 4) ? x10[qq] : x11[qq - 4];
        uint32_t pk = (uint32_t)(unsigned short)f2bf(va) |
                      ((uint32_t)(unsigned short)f2bf(vb) << 16);
        lB32[((pg * 8 + qq) * 40 + 2 * cpair) >> 1] = pk;
      }
    } else {
      *(short8*)(lB + sr * 40 + sk) = b0;
      *(short8*)(lB + (sr + 64) * 40 + sk) = b1;
    }
    __syncthreads();
    short8 af[4], bfr[4];
#pragma unroll
    for (int m = 0; m < 4; ++m) af[m]  = *(const short8*)(lA + (wm + m * 16 + fr) * 40 + fo * 8);
#pragma unroll
    for (int n = 0; n < 4; ++n) bfr[n] = *(const short8*)(lB + (wn + n * 16 + fr) * 40 + fo * 8);
#pragma unroll
    for (int m = 0; m < 4; ++m)
#pragma unroll
      for (int n = 0; n < 4; ++n)
        acc[m][n] = __builtin_amdgcn_mfma_f32_16x16x32_bf16(af[m], bfr[n], acc[m][n], 0, 0, 0);
  }
  if (MODE == 0) {
    if (om0 < 768) {     // q & k -> qk[b][p][768]
      short* outq = (short*)o1 + (size_t)b * HWsz * 768;
#pragma unroll
      for (int m = 0; m < 4; ++m) {
        int ob = om0 + wm + m * 16 + (lane >> 4) * 4;
        float bs[4];
#pragma unroll
        for (int r = 0; r < 4; ++r) { int o = ob + r; bs[r] = bias[o] * (o < Cc ? 0.125f : 1.0f); }
#pragma unroll
        for (int n = 0; n < 4; ++n) {
          int p = pn0 + wn + n * 16 + fr;
          if (p < HWsz) {
            short4v s;
#pragma unroll
            for (int r = 0; r < 4; ++r) s[r] = f2bf(acc[m][n][r] + bs[r]);
            *(short4v*)(outq + (size_t)p * 768 + ob) = s;
          }
        }
      }
    } else {             // v -> vtp[b][ch][62][64] padded (border pre-zeroed)
      short* vtp = (short*)o2;
#pragma unroll
      for (int m = 0; m < 4; ++m) {
        int ob = om0 + wm + m * 16 + (lane >> 4) * 4;
#pragma unroll
        for (int n = 0; n < 4; ++n) {
          int p = pn0 + wn + n * 16 + fr;
          if (p < HWsz) {
            int ii = p / Hh, jj = p % Hh;
#pragma unroll
            for (int r = 0; r < 4; ++r) {
              int ch = ob + r - 768;
              vtp[((b * Cc + ch) * 62 + ii + 3) * 64 + jj + 3] = f2bf(acc[m][n][r] + bias[ob + r]);
            }
          }
        }
      }
    }
  } else {
    float* outo = (float*)o1 + (size_t)b * Cc * HWsz;
#pragma unroll
    for (int m = 0; m < 4; ++m) {
      int ob = om0 + wm + m * 16 + (lane >> 4) * 4;
#pragma unroll
      for (int n = 0; n < 4; ++n) {
        int p = pn0 + wn + n * 16 + fr;
        if (p < HWsz) {
#pragma unroll
          for (int r = 0; r < 4; ++r)
            outo[(size_t)(ob + r) * HWsz + p] = acc[m][n][r] + bias[ob + r];
        }
      }
    }
  }
}

// ---------------- MFMA neighborhood attention
// 1-D grid 2352: b = blk & 7 (XCD pin); r = blk>>3; h = r/49 (h-major: per-(b,h)
// working set ~1.2MB stays L2-hot for a whole h-sweep); tile = r%49 -> 8x8 queries.
__global__ __launch_bounds__(256) void attn_mfma(
    const short* __restrict__ qkv,  // [b][3136][768] (q|k)
    const short* __restrict__ vtp,  // [b][384][62][64]
    short* __restrict__ aout)       // [b][3136][384]
{
  __shared__ short P[64 * 40];
  const int blk = blockIdx.x;
  const int b = blk & 7;
  const int r_ = blk >> 3;
  const int h = r_ / 49;
  const int tile = r_ % 49;
  const int i0 = (tile / 7) * 8, j0 = (tile % 7) * 8;
  const int t = threadIdx.x, lane = t & 63, w = t >> 6;
  const int fr = lane & 15, fo = lane >> 4;

  const int q_idx = w * 16 + fr;
  const int qr = q_idx >> 3, qc = q_idx & 7;
  const int qkvb = b * HWsz * 768;

  const short* qp = qkv + qkvb + ((i0 + qr) * Hh + j0 + qc) * 768 + h * 64 + fo * 8;
  short8 qf0 = *(const short8*)(qp);
  short8 qf1 = *(const short8*)(qp + 32);

  const int kj = j0 + fr - 3;
  const bool jok = (unsigned)kj < (unsigned)Hh;
  const int kjs = kj < 0 ? 0 : (kj > Hh - 1 ? Hh - 1 : kj);
  const short* kcol = qkv + qkvb + Cc + h * 64 + fo * 8;

  const short8 z = (short8)0;
  f32x4 oacc[4] = {};
  float sum = 0.f;

#pragma unroll 2
  for (int kc = 0; kc < 7; ++kc) {
    short8 kf[2][2];
#pragma unroll
    for (int mloc = 0; mloc < 2; ++mloc) {
      int ki = i0 + 2 * kc + mloc - 3;
      bool ok = jok && ((unsigned)ki < (unsigned)Hh);
      int kis = ki < 0 ? 0 : (ki > Hh - 1 ? Hh - 1 : ki);
      const short8* ka = (const short8*)(kcol + (kis * Hh + kjs) * 768);
      short8 k0 = ka[0], k1 = ka[4];
      kf[mloc][0] = ok ? k0 : z;
      kf[mloc][1] = ok ? k1 : z;
    }
    short8 vf[4];
    const int vrow = i0 + 2 * kc + (fo >> 1);
    const int vcol = j0 + (fo & 1) * 8;
#pragma unroll
    for (int n = 0; n < 4; ++n)
      vf[n] = *(const short8*)(vtp + ((b * Cc + h * 64 + 16 * n + fr) * 62 + vrow) * 64 + vcol);
    f32x4 s0 = {}, s1 = {};
    s0 = __builtin_amdgcn_mfma_f32_16x16x32_bf16(kf[0][0], qf0, s0, 0, 0, 0);
    s0 = __builtin_amdgcn_mfma_f32_16x16x32_bf16(kf[0][1], qf1, s0, 0, 0, 0);
    s1 = __builtin_amdgcn_mfma_f32_16x16x32_bf16(kf[1][0], qf0, s1, 0, 0, 0);
    s1 = __builtin_amdgcn_mfma_f32_16x16x32_bf16(kf[1][1], qf1, s1, 0, 0, 0);
#pragma unroll
    for (int mloc = 0; mloc < 2; ++mloc) {
      const f32x4 sv = mloc ? s1 : s0;
      int dpr = 2 * kc + mloc - qr;
      bool rok = (unsigned)dpr <= 6u;
      short4v pk;
#pragma unroll
      for (int r = 0; r < 4; ++r) {
        int dpc = fo * 4 + r - qc;
        float e = (rok && (unsigned)dpc <= 6u) ? __expf(sv[r]) : 0.f;
        sum += e;
        pk[r] = f2bf(e);
      }
      *(short4v*)(P + q_idx * 40 + mloc * 16 + fo * 4) = pk;
    }
    short8 pa = *(const short8*)(P + q_idx * 40 + fo * 8);
#pragma unroll
    for (int n = 0; n < 4; ++n)
      oacc[n] = __builtin_amdgcn_mfma_f32_16x16x32_bf16(pa, vf[n], oacc[n], 0, 0, 0);
  }

  sum += __shfl_xor(sum, 16);
  sum += __shfl_xor(sum, 32);
  float inv[4];
#pragma unroll
  for (int r = 0; r < 4; ++r) inv[r] = 1.0f / __shfl(sum, fo * 4 + r);
  const int owr = i0 + 2 * w + (fo >> 1);
  const int owc = j0 + (fo & 1) * 4;
#pragma unroll
  for (int n = 0; n < 4; ++n)
#pragma unroll
    for (int r = 0; r < 4; ++r)
      aout[(size_t)(b * HWsz + owr * Hh + owc + r) * Cc + h * 64 + 16 * n + fr] =
          f2bf(oacc[n][r] * inv[r]);
}

extern "C" void kernel_launch(void* const* d_in, const int* in_sizes, int n_in,
                              void* d_out, int out_size, void* d_ws, size_t ws_size,
                              hipStream_t stream) {
  const float* x      = (const float*)d_in[0];
  const float* w_qkv  = (const float*)d_in[1];
  const float* b_qkv  = (const float*)d_in[2];
  const float* w_proj = (const float*)d_in[3];
  const float* b_proj = (const float*)d_in[4];

  char* ws = (char*)d_ws;
  // qk 38,535,168 | vtp 24,379,392 | aout 19,267,584 | wqb 884,736 | wpb 294,912 = 83.4 MB
  short* qk   = (short*)ws;
  short* vtp  = (short*)(ws + 38535168);
  short* aout = (short*)(ws + 38535168 + 24379392);
  short* wqb  = (short*)(ws + 38535168 + 24379392 + 19267584);
  short* wpb  = (short*)(ws + 38535168 + 24379392 + 19267584 + 884736);

  prep_weights<<<512, 256, 0, stream>>>(w_qkv, w_proj, wqb, wpb);
  hipMemsetAsync(vtp, 0, 24379392, stream);     // zero-pad borders for V image
  gemm_bf16<0><<<8 * 225, 256, 0, stream>>>(wqb, x, b_qkv, qk, vtp);
  attn_mfma<<<8 * 294, 256, 0, stream>>>(qk, vtp, aout);
  gemm_bf16<1><<<8 * 75, 256, 0, stream>>>(wpb, aout, b_proj, d_out, nullptr);
}

// Round 8
// 252.768 us; speedup vs baseline: 1.0324x; 1.0324x over previous
//
#include <hip/hip_runtime.h>
#include <hip/hip_bf16.h>
#include <stdint.h>

#define HWsz 3136
#define Hh   56
#define Cc   384
#define NHEADS 6
#define NB   8

typedef __attribute__((ext_vector_type(8))) short short8;
typedef __attribute__((ext_vector_type(4))) short short4v;
typedef __attribute__((ext_vector_type(4))) float f32x4;

static __device__ __forceinline__ short f2bf(float f) {
  __hip_bfloat16 h = __float2bfloat16(f);
  return (short)__builtin_bit_cast(unsigned short, h);
}

// ---------------- weight conversion (fold q-scale 0.125 into first 384 rows of w_qkv)
__global__ void prep_weights(const float* __restrict__ wq, const float* __restrict__ wp,
                             short* __restrict__ wqb, short* __restrict__ wpb) {
  int stride = gridDim.x * blockDim.x;
  for (int i = blockIdx.x * blockDim.x + threadIdx.x; i < 3 * Cc * Cc; i += stride) {
    float v = wq[i];
    if (i < Cc * Cc) v *= 0.125f;
    wqb[i] = f2bf(v);
  }
  for (int i = blockIdx.x * blockDim.x + threadIdx.x; i < Cc * Cc; i += stride)
    wpb[i] = f2bf(wp[i]);
}

// ---------------- bf16 MFMA GEMM: D[o,p] = sum_k A[o][k]*B[k][p-ish], K=384
// 1-D grid, b = blockIdx.x & 7  -> XCD b owns batch b.
// lB is XOR-swizzled: k-word w of row r lives at word w ^ (((r>>3)&3)<<2).
// Write side (MODE0 b32 scatter): bank = qq*20 + (cpair ^ ((pg&3)<<2)) -> 4-way
// (was 16-way: pg-stride 160 words = 0 mod 32). Reads stay b128, 16B-aligned.
// MODE 0: B = x f32 [b][c][3136] (transpose fused in staging);
//         o<768 -> qk[b][p][768] bf16; o>=768 -> vtp[b][ch][62][64] padded image
// MODE 1: B = attn_out bf16 [b][p][384] rows; out f32 [b][o][3136]
template<int MODE>
__global__ __launch_bounds__(256) void gemm_bf16(
    const short* __restrict__ A, const void* __restrict__ Bsrc,
    const float* __restrict__ bias, void* __restrict__ o1, void* __restrict__ o2)
{
  constexpr int K = Cc;
  constexpr int NOM = (MODE == 0 ? 9 : 3);
  const int b   = blockIdx.x & 7;
  const int idx = blockIdx.x >> 3;
  const int om0 = (idx % NOM) * 128;
  const int pn0 = (idx / NOM) * 128;
  __shared__ short lA[128 * 40];
  __shared__ short lB[128 * 40];
  const int t    = threadIdx.x;
  const int lane = t & 63;
  const int wave = t >> 6;
  const int wm = (wave >> 1) * 64;
  const int wn = (wave & 1) * 64;
  f32x4 acc[4][4] = {};
  const int fr = lane & 15;
  const int fo = lane >> 4;
  // A staging map (both modes)
  const int sr = t >> 2;
  const int sk = (t & 3) * 8;
  // MODE0 B staging map: 16 c-pairs x 16 p-groups of 8
  const int pg = t & 15, cpair = t >> 4;
  const int pbase = pn0 + pg * 8;
  const int po0 = pbase     > HWsz - 4 ? HWsz - 4 : pbase;
  const int po1 = pbase + 4 > HWsz - 4 ? HWsz - 4 : pbase + 4;
  const float* Bx = (const float*)Bsrc + (size_t)b * Cc * HWsz;
  // MODE1 B staging map
  const short* Bb = (const short*)Bsrc + (size_t)b * HWsz * K;
  int pr0 = pn0 + sr;      if (pr0 > HWsz - 1) pr0 = HWsz - 1;
  int pr1 = pn0 + sr + 64; if (pr1 > HWsz - 1) pr1 = HWsz - 1;

  for (int k0 = 0; k0 < K; k0 += 32) {
    short8 a0 = *(const short8*)(A + (size_t)(om0 + sr) * K + k0 + sk);
    short8 a1 = *(const short8*)(A + (size_t)(om0 + sr + 64) * K + k0 + sk);
    f32x4 x00, x01, x10, x11; short8 b0, b1;
    if (MODE == 0) {
      const float* r0 = Bx + (size_t)(k0 + 2 * cpair) * HWsz;
      x00 = *(const f32x4*)(r0 + po0);
      x01 = *(const f32x4*)(r0 + po1);
      x10 = *(const f32x4*)(r0 + HWsz + po0);
      x11 = *(const f32x4*)(r0 + HWsz + po1);
    } else {
      b0 = *(const short8*)(Bb + (size_t)pr0 * K + k0 + sk);
      b1 = *(const short8*)(Bb + (size_t)pr1 * K + k0 + sk);
    }
    __syncthreads();
    *(short8*)(lA + sr * 40 + sk) = a0;
    *(short8*)(lA + (sr + 64) * 40 + sk) = a1;
    if (MODE == 0) {
      uint32_t* lB32 = (uint32_t*)lB;
      const int wcol = cpair ^ ((pg & 3) << 2);   // swizzled k-word slot
#pragma unroll
      for (int qq = 0; qq < 8; ++qq) {
        float va = (qq < 4) ? x00[qq] : x01[qq - 4];
        float vb = (qq < 4) ? x10[qq] : x11[qq - 4];
        uint32_t pk = (uint32_t)(unsigned short)f2bf(va) |
                      ((uint32_t)(unsigned short)f2bf(vb) << 16);
        lB32[(pg * 8 + qq) * 20 + wcol] = pk;
      }
    } else {
      const int key0 = (sr >> 3) & 3;             // rows sr and sr+64 share key
      *(short8*)(lB + sr * 40 + 8 * ((sk >> 3) ^ key0)) = b0;
      *(short8*)(lB + (sr + 64) * 40 + 8 * ((sk >> 3) ^ key0)) = b1;
    }
    __syncthreads();
    short8 af[4], bfr[4];
#pragma unroll
    for (int m = 0; m < 4; ++m) af[m]  = *(const short8*)(lA + (wm + m * 16 + fr) * 40 + fo * 8);
#pragma unroll
    for (int n = 0; n < 4; ++n) {
      const int r = wn + n * 16 + fr;
      bfr[n] = *(const short8*)(lB + r * 40 + 8 * (fo ^ ((r >> 3) & 3)));
    }
#pragma unroll
    for (int m = 0; m < 4; ++m)
#pragma unroll
      for (int n = 0; n < 4; ++n)
        acc[m][n] = __builtin_amdgcn_mfma_f32_16x16x32_bf16(af[m], bfr[n], acc[m][n], 0, 0, 0);
  }
  if (MODE == 0) {
    if (om0 < 768) {     // q & k -> qk[b][p][768]
      short* outq = (short*)o1 + (size_t)b * HWsz * 768;
#pragma unroll
      for (int m = 0; m < 4; ++m) {
        int ob = om0 + wm + m * 16 + (lane >> 4) * 4;
        float bs[4];
#pragma unroll
        for (int r = 0; r < 4; ++r) { int o = ob + r; bs[r] = bias[o] * (o < Cc ? 0.125f : 1.0f); }
#pragma unroll
        for (int n = 0; n < 4; ++n) {
          int p = pn0 + wn + n * 16 + fr;
          if (p < HWsz) {
            short4v s;
#pragma unroll
            for (int r = 0; r < 4; ++r) s[r] = f2bf(acc[m][n][r] + bs[r]);
            *(short4v*)(outq + (size_t)p * 768 + ob) = s;
          }
        }
      }
    } else {             // v -> vtp[b][ch][62][64] padded (border pre-zeroed)
      short* vtp = (short*)o2;
#pragma unroll
      for (int m = 0; m < 4; ++m) {
        int ob = om0 + wm + m * 16 + (lane >> 4) * 4;
#pragma unroll
        for (int n = 0; n < 4; ++n) {
          int p = pn0 + wn + n * 16 + fr;
          if (p < HWsz) {
            int ii = p / Hh, jj = p % Hh;
#pragma unroll
            for (int r = 0; r < 4; ++r) {
              int ch = ob + r - 768;
              vtp[((b * Cc + ch) * 62 + ii + 3) * 64 + jj + 3] = f2bf(acc[m][n][r] + bias[ob + r]);
            }
          }
        }
      }
    }
  } else {
    float* outo = (float*)o1 + (size_t)b * Cc * HWsz;
#pragma unroll
    for (int m = 0; m < 4; ++m) {
      int ob = om0 + wm + m * 16 + (lane >> 4) * 4;
#pragma unroll
      for (int n = 0; n < 4; ++n) {
        int p = pn0 + wn + n * 16 + fr;
        if (p < HWsz) {
#pragma unroll
          for (int r = 0; r < 4; ++r)
            outo[(size_t)(ob + r) * HWsz + p] = acc[m][n][r] + bias[ob + r];
        }
      }
    }
  }
}

// ---------------- MFMA neighborhood attention
// 1-D grid 2352: b = blk & 7 (XCD pin); r = blk>>3; h = r/49 (h-major: per-(b,h)
// working set ~1.2MB stays L2-hot for a whole h-sweep); tile = r%49 -> 8x8 queries.
__global__ __launch_bounds__(256) void attn_mfma(
    const short* __restrict__ qkv,  // [b][3136][768] (q|k)
    const short* __restrict__ vtp,  // [b][384][62][64]
    short* __restrict__ aout)       // [b][3136][384]
{
  __shared__ short P[64 * 40];
  const int blk = blockIdx.x;
  const int b = blk & 7;
  const int r_ = blk >> 3;
  const int h = r_ / 49;
  const int tile = r_ % 49;
  const int i0 = (tile / 7) * 8, j0 = (tile % 7) * 8;
  const int t = threadIdx.x, lane = t & 63, w = t >> 6;
  const int fr = lane & 15, fo = lane >> 4;

  const int q_idx = w * 16 + fr;
  const int qr = q_idx >> 3, qc = q_idx & 7;
  const int qkvb = b * HWsz * 768;

  const short* qp = qkv + qkvb + ((i0 + qr) * Hh + j0 + qc) * 768 + h * 64 + fo * 8;
  short8 qf0 = *(const short8*)(qp);
  short8 qf1 = *(const short8*)(qp + 32);

  const int kj = j0 + fr - 3;
  const bool jok = (unsigned)kj < (unsigned)Hh;
  const int kjs = kj < 0 ? 0 : (kj > Hh - 1 ? Hh - 1 : kj);
  const short* kcol = qkv + qkvb + Cc + h * 64 + fo * 8;

  const short8 z = (short8)0;
  f32x4 oacc[4] = {};
  float sum = 0.f;

#pragma unroll 2
  for (int kc = 0; kc < 7; ++kc) {
    short8 kf[2][2];
#pragma unroll
    for (int mloc = 0; mloc < 2; ++mloc) {
      int ki = i0 + 2 * kc + mloc - 3;
      bool ok = jok && ((unsigned)ki < (unsigned)Hh);
      int kis = ki < 0 ? 0 : (ki > Hh - 1 ? Hh - 1 : ki);
      const short8* ka = (const short8*)(kcol + (kis * Hh + kjs) * 768);
      short8 k0 = ka[0], k1 = ka[4];
      kf[mloc][0] = ok ? k0 : z;
      kf[mloc][1] = ok ? k1 : z;
    }
    short8 vf[4];
    const int vrow = i0 + 2 * kc + (fo >> 1);
    const int vcol = j0 + (fo & 1) * 8;
#pragma unroll
    for (int n = 0; n < 4; ++n)
      vf[n] = *(const short8*)(vtp + ((b * Cc + h * 64 + 16 * n + fr) * 62 + vrow) * 64 + vcol);
    f32x4 s0 = {}, s1 = {};
    s0 = __builtin_amdgcn_mfma_f32_16x16x32_bf16(kf[0][0], qf0, s0, 0, 0, 0);
    s0 = __builtin_amdgcn_mfma_f32_16x16x32_bf16(kf[0][1], qf1, s0, 0, 0, 0);
    s1 = __builtin_amdgcn_mfma_f32_16x16x32_bf16(kf[1][0], qf0, s1, 0, 0, 0);
    s1 = __builtin_amdgcn_mfma_f32_16x16x32_bf16(kf[1][1], qf1, s1, 0, 0, 0);
#pragma unroll
    for (int mloc = 0; mloc < 2; ++mloc) {
      const f32x4 sv = mloc ? s1 : s0;
      int dpr = 2 * kc + mloc - qr;
      bool rok = (unsigned)dpr <= 6u;
      short4v pk;
#pragma unroll
      for (int r = 0; r < 4; ++r) {
        int dpc = fo * 4 + r - qc;
        float e = (rok && (unsigned)dpc <= 6u) ? __expf(sv[r]) : 0.f;
        sum += e;
        pk[r] = f2bf(e);
      }
      *(short4v*)(P + q_idx * 40 + mloc * 16 + fo * 4) = pk;
    }
    short8 pa = *(const short8*)(P + q_idx * 40 + fo * 8);
#pragma unroll
    for (int n = 0; n < 4; ++n)
      oacc[n] = __builtin_amdgcn_mfma_f32_16x16x32_bf16(pa, vf[n], oacc[n], 0, 0, 0);
  }

  sum += __shfl_xor(sum, 16);
  sum += __shfl_xor(sum, 32);
  float inv[4];
#pragma unroll
  for (int r = 0; r < 4; ++r) inv[r] = 1.0f / __shfl(sum, fo * 4 + r);
  const int owr = i0 + 2 * w + (fo >> 1);
  const int owc = j0 + (fo & 1) * 4;
#pragma unroll
  for (int n = 0; n < 4; ++n)
#pragma unroll
    for (int r = 0; r < 4; ++r)
      aout[(size_t)(b * HWsz + owr * Hh + owc + r) * Cc + h * 64 + 16 * n + fr] =
          f2bf(oacc[n][r] * inv[r]);
}

extern "C" void kernel_launch(void* const* d_in, const int* in_sizes, int n_in,
                              void* d_out, int out_size, void* d_ws, size_t ws_size,
                              hipStream_t stream) {
  const float* x      = (const float*)d_in[0];
  const float* w_qkv  = (const float*)d_in[1];
  const float* b_qkv  = (const float*)d_in[2];
  const float* w_proj = (const float*)d_in[3];
  const float* b_proj = (const float*)d_in[4];

  char* ws = (char*)d_ws;
  // qk 38,535,168 | vtp 24,379,392 | aout 19,267,584 | wqb 884,736 | wpb 294,912 = 83.4 MB
  short* qk   = (short*)ws;
  short* vtp  = (short*)(ws + 38535168);
  short* aout = (short*)(ws + 38535168 + 24379392);
  short* wqb  = (short*)(ws + 38535168 + 24379392 + 19267584);
  short* wpb  = (short*)(ws + 38535168 + 24379392 + 19267584 + 884736);

  prep_weights<<<512, 256, 0, stream>>>(w_qkv, w_proj, wqb, wpb);
  hipMemsetAsync(vtp, 0, 24379392, stream);     // zero-pad borders for V image
  gemm_bf16<0><<<8 * 225, 256, 0, stream>>>(wqb, x, b_qkv, qk, vtp);
  attn_mfma<<<8 * 294, 256, 0, stream>>>(qk, vtp, aout);
  gemm_bf16<1><<<8 * 75, 256, 0, stream>>>(wpb, aout, b_proj, d_out, nullptr);
}

// Round 9
// 236.818 us; speedup vs baseline: 1.1019x; 1.0674x over previous
//
#include <hip/hip_runtime.h>
#include <hip/hip_bf16.h>
#include <stdint.h>

#define HWsz 3136
#define Hh   56
#define Cc   384
#define NHEADS 6
#define NB   8

typedef __attribute__((ext_vector_type(8))) short short8;
typedef __attribute__((ext_vector_type(4))) short short4v;
typedef __attribute__((ext_vector_type(4))) float f32x4;

static __device__ __forceinline__ short f2bf(float f) {
  __hip_bfloat16 h = __float2bfloat16(f);
  return (short)__builtin_bit_cast(unsigned short, h);
}
// async global->LDS, 16B per lane: lds gets base + lane*16, src is per-lane
static __device__ __forceinline__ void gload16(const void* g, void* l) {
  __builtin_amdgcn_global_load_lds(
      (const __attribute__((address_space(1))) void*)g,
      (__attribute__((address_space(3))) void*)l, 16, 0, 0);
}

// ---------------- weight prep: convert to bf16 into TILED layout [om][12][128][40]
// (LDS-image tiles, 8 pad shorts/row; pads never read). q rows scaled by 0.125.
__global__ void prep_weights(const float* __restrict__ wq, const float* __restrict__ wp,
                             short* __restrict__ wqt, short* __restrict__ wpt) {
  int stride = gridDim.x * blockDim.x;
  for (int i = blockIdx.x * blockDim.x + threadIdx.x; i < 3 * Cc * Cc; i += stride) {
    int o = i / Cc, k = i - o * Cc;
    float v = wq[i] * (o < Cc ? 0.125f : 1.0f);
    wqt[(((o >> 7) * 12 + (k >> 5)) * 128 + (o & 127)) * 40 + (k & 31)] = f2bf(v);
  }
  for (int i = blockIdx.x * blockDim.x + threadIdx.x; i < Cc * Cc; i += stride) {
    int o = i / Cc, k = i - o * Cc;
    wpt[(((o >> 7) * 12 + (k >> 5)) * 128 + (o & 127)) * 40 + (k & 31)] = f2bf(wp[i]);
  }
}

// ---------------- x (B,C,HW) f32 -> tiled bf16 xTt[b][pn=25][k0=12][128][40]
// block = (b, pn, kg); kg covers 3 k0-chunks. b = blk&7 -> XCD pin.
__global__ __launch_bounds__(256) void transpose_x(const float* __restrict__ x,
                                                   short* __restrict__ xTt) {
  __shared__ float tf[32][129];
  const int blk = blockIdx.x;
  const int b = blk & 7;
  const int idx = blk >> 3;
  const int pni = idx >> 2;
  const int kg  = idx & 3;
  const int p0 = pni * 128;
  const int t = threadIdx.x;
  const float* xb = x + (size_t)b * Cc * HWsz;
  short* outb = xTt + ((size_t)(b * 25 + pni)) * 12 * 5120;
  const int cc = t >> 3, pq = t & 7;      // load map: c-row, p-group of 16
  const int orow = t >> 1, ohf = t & 1;   // store map: out row, k-half
  for (int k0 = kg * 3; k0 < kg * 3 + 3; ++k0) {
    const float* crow = xb + (size_t)(k0 * 32 + cc) * HWsz;
#pragma unroll
    for (int i = 0; i < 4; ++i) {
      int p = p0 + pq * 16 + i * 4;
      if (p > HWsz - 4) p = HWsz - 4;     // clamp tail tile (dup values, discarded later)
      f32x4 v = *(const f32x4*)(crow + p);
      tf[cc][pq * 16 + i * 4 + 0] = v[0];
      tf[cc][pq * 16 + i * 4 + 1] = v[1];
      tf[cc][pq * 16 + i * 4 + 2] = v[2];
      tf[cc][pq * 16 + i * 4 + 3] = v[3];
    }
    __syncthreads();
    short8 s0, s1;
#pragma unroll
    for (int i = 0; i < 8; ++i) s0[i] = f2bf(tf[ohf * 16 + i][orow]);
#pragma unroll
    for (int i = 0; i < 8; ++i) s1[i] = f2bf(tf[ohf * 16 + 8 + i][orow]);
    short* orp = outb + k0 * 5120 + orow * 40 + ohf * 16;
    *(short8*)(orp)     = s0;
    *(short8*)(orp + 8) = s1;
    __syncthreads();
  }
}

// ---------------- bf16 MFMA GEMM, m97-style: global_load_lds both operands.
// A = tiled weights [NOM][12][128][40]; B = tiled activations [8][25][12][128][40].
// Per K-step: 20x gload16 (5/wave), 2 barriers, 8 ds_read_b128, 16 MFMA.
// 1-D grid, b = blk&7 (XCD pin), om fast (B-panel L2-resident across om-blocks).
// MODE 0: o<768 -> qk[b][p][768]; o>=768 -> vtp[b][ch][62][64] padded image
// MODE 1: out f32 [b][o][3136]
template<int MODE>
__global__ __launch_bounds__(256) void gemm_bf16(
    const short* __restrict__ At, const short* __restrict__ Bt,
    const float* __restrict__ bias, void* __restrict__ o1, void* __restrict__ o2)
{
  constexpr int NOM = (MODE == 0 ? 9 : 3);
  const int b   = blockIdx.x & 7;
  const int idx = blockIdx.x >> 3;
  const int omi = idx % NOM;
  const int pni = idx / NOM;
  const int om0 = omi * 128, pn0 = pni * 128;
  __shared__ short lA[5120];
  __shared__ short lB[5120];
  const int t = threadIdx.x, lane = t & 63, wave = t >> 6;
  const int wm = (wave >> 1) * 64, wn = (wave & 1) * 64;
  const int fr = lane & 15, fo = lane >> 4;
  f32x4 acc[4][4] = {};
  const short* Abase = At + omi * 12 * 5120;
  const short* Bbase = Bt + ((size_t)(b * 25 + pni)) * 12 * 5120;

  for (int k0i = 0; k0i < 12; ++k0i) {
    __syncthreads();                     // prev tile's frag reads complete
    const short* Ats = Abase + k0i * 5120;
    const short* Bts = Bbase + k0i * 5120;
#pragma unroll
    for (int c = 0; c < 5; ++c) {
      const int g = wave * 5 + c;        // wave-uniform chunk id 0..19
      const short* src = (g < 10 ? Ats + g * 512 : Bts + (g - 10) * 512) + lane * 8;
      short* dst = (g < 10 ? lA + g * 512 : lB + (g - 10) * 512);
      gload16(src, dst);
    }
    __syncthreads();                     // compiler drains vmcnt(0) before barrier
    short8 af[4], bfr[4];
#pragma unroll
    for (int m = 0; m < 4; ++m) af[m]  = *(const short8*)(lA + (wm + m * 16 + fr) * 40 + fo * 8);
#pragma unroll
    for (int n = 0; n < 4; ++n) bfr[n] = *(const short8*)(lB + (wn + n * 16 + fr) * 40 + fo * 8);
#pragma unroll
    for (int m = 0; m < 4; ++m)
#pragma unroll
      for (int n = 0; n < 4; ++n)
        acc[m][n] = __builtin_amdgcn_mfma_f32_16x16x32_bf16(af[m], bfr[n], acc[m][n], 0, 0, 0);
  }
  if (MODE == 0) {
    if (om0 < 768) {     // q & k -> qk[b][p][768]
      short* outq = (short*)o1 + (size_t)b * HWsz * 768;
#pragma unroll
      for (int m = 0; m < 4; ++m) {
        int ob = om0 + wm + m * 16 + (lane >> 4) * 4;
        float bs[4];
#pragma unroll
        for (int r = 0; r < 4; ++r) { int o = ob + r; bs[r] = bias[o] * (o < Cc ? 0.125f : 1.0f); }
#pragma unroll
        for (int n = 0; n < 4; ++n) {
          int p = pn0 + wn + n * 16 + fr;
          if (p < HWsz) {
            short4v s;
#pragma unroll
            for (int r = 0; r < 4; ++r) s[r] = f2bf(acc[m][n][r] + bs[r]);
            *(short4v*)(outq + (size_t)p * 768 + ob) = s;
          }
        }
      }
    } else {             // v -> vtp[b][ch][62][64] padded (border pre-zeroed)
      short* vtp = (short*)o2;
#pragma unroll
      for (int m = 0; m < 4; ++m) {
        int ob = om0 + wm + m * 16 + (lane >> 4) * 4;
#pragma unroll
        for (int n = 0; n < 4; ++n) {
          int p = pn0 + wn + n * 16 + fr;
          if (p < HWsz) {
            int ii = p / Hh, jj = p % Hh;
#pragma unroll
            for (int r = 0; r < 4; ++r) {
              int ch = ob + r - 768;
              vtp[((b * Cc + ch) * 62 + ii + 3) * 64 + jj + 3] = f2bf(acc[m][n][r] + bias[ob + r]);
            }
          }
        }
      }
    }
  } else {
    float* outo = (float*)o1 + (size_t)b * Cc * HWsz;
#pragma unroll
    for (int m = 0; m < 4; ++m) {
      int ob = om0 + wm + m * 16 + (lane >> 4) * 4;
#pragma unroll
      for (int n = 0; n < 4; ++n) {
        int p = pn0 + wn + n * 16 + fr;
        if (p < HWsz) {
#pragma unroll
          for (int r = 0; r < 4; ++r)
            outo[(size_t)(ob + r) * HWsz + p] = acc[m][n][r] + bias[ob + r];
        }
      }
    }
  }
}

// ---------------- MFMA neighborhood attention (unchanged core)
// Output now written in TILED layout aoutT[b][pn][k0][128][40] for gemm1's gload_lds.
__global__ __launch_bounds__(256) void attn_mfma(
    const short* __restrict__ qkv,  // [b][3136][768] (q|k)
    const short* __restrict__ vtp,  // [b][384][62][64]
    short* __restrict__ aoutT)      // [b][25][12][128][40]
{
  __shared__ short P[64 * 40];
  const int blk = blockIdx.x;
  const int b = blk & 7;
  const int r_ = blk >> 3;
  const int h = r_ / 49;
  const int tile = r_ % 49;
  const int i0 = (tile / 7) * 8, j0 = (tile % 7) * 8;
  const int t = threadIdx.x, lane = t & 63, w = t >> 6;
  const int fr = lane & 15, fo = lane >> 4;

  const int q_idx = w * 16 + fr;
  const int qr = q_idx >> 3, qc = q_idx & 7;
  const int qkvb = b * HWsz * 768;

  const short* qp = qkv + qkvb + ((i0 + qr) * Hh + j0 + qc) * 768 + h * 64 + fo * 8;
  short8 qf0 = *(const short8*)(qp);
  short8 qf1 = *(const short8*)(qp + 32);

  const int kj = j0 + fr - 3;
  const bool jok = (unsigned)kj < (unsigned)Hh;
  const int kjs = kj < 0 ? 0 : (kj > Hh - 1 ? Hh - 1 : kj);
  const short* kcol = qkv + qkvb + Cc + h * 64 + fo * 8;

  const short8 z = (short8)0;
  f32x4 oacc[4] = {};
  float sum = 0.f;

#pragma unroll 2
  for (int kc = 0; kc < 7; ++kc) {
    short8 kf[2][2];
#pragma unroll
    for (int mloc = 0; mloc < 2; ++mloc) {
      int ki = i0 + 2 * kc + mloc - 3;
      bool ok = jok && ((unsigned)ki < (unsigned)Hh);
      int kis = ki < 0 ? 0 : (ki > Hh - 1 ? Hh - 1 : ki);
      const short8* ka = (const short8*)(kcol + (kis * Hh + kjs) * 768);
      short8 k0 = ka[0], k1 = ka[4];
      kf[mloc][0] = ok ? k0 : z;
      kf[mloc][1] = ok ? k1 : z;
    }
    short8 vf[4];
    const int vrow = i0 + 2 * kc + (fo >> 1);
    const int vcol = j0 + (fo & 1) * 8;
#pragma unroll
    for (int n = 0; n < 4; ++n)
      vf[n] = *(const short8*)(vtp + ((b * Cc + h * 64 + 16 * n + fr) * 62 + vrow) * 64 + vcol);
    f32x4 s0 = {}, s1 = {};
    s0 = __builtin_amdgcn_mfma_f32_16x16x32_bf16(kf[0][0], qf0, s0, 0, 0, 0);
    s0 = __builtin_amdgcn_mfma_f32_16x16x32_bf16(kf[0][1], qf1, s0, 0, 0, 0);
    s1 = __builtin_amdgcn_mfma_f32_16x16x32_bf16(kf[1][0], qf0, s1, 0, 0, 0);
    s1 = __builtin_amdgcn_mfma_f32_16x16x32_bf16(kf[1][1], qf1, s1, 0, 0, 0);
#pragma unroll
    for (int mloc = 0; mloc < 2; ++mloc) {
      const f32x4 sv = mloc ? s1 : s0;
      int dpr = 2 * kc + mloc - qr;
      bool rok = (unsigned)dpr <= 6u;
      short4v pk;
#pragma unroll
      for (int r = 0; r < 4; ++r) {
        int dpc = fo * 4 + r - qc;
        float e = (rok && (unsigned)dpc <= 6u) ? __expf(sv[r]) : 0.f;
        sum += e;
        pk[r] = f2bf(e);
      }
      *(short4v*)(P + q_idx * 40 + mloc * 16 + fo * 4) = pk;
    }
    short8 pa = *(const short8*)(P + q_idx * 40 + fo * 8);
#pragma unroll
    for (int n = 0; n < 4; ++n)
      oacc[n] = __builtin_amdgcn_mfma_f32_16x16x32_bf16(pa, vf[n], oacc[n], 0, 0, 0);
  }

  sum += __shfl_xor(sum, 16);
  sum += __shfl_xor(sum, 32);
  float inv[4];
#pragma unroll
  for (int r = 0; r < 4; ++r) inv[r] = 1.0f / __shfl(sum, fo * 4 + r);
  const int owr = i0 + 2 * w + (fo >> 1);
  const int owc = j0 + (fo & 1) * 4;
  short* ab = aoutT + (size_t)b * 25 * 12 * 5120;
#pragma unroll
  for (int n = 0; n < 4; ++n) {
    const int k0 = 2 * h + (n >> 1);
    const int kk = 16 * (n & 1) + fr;
#pragma unroll
    for (int r = 0; r < 4; ++r) {
      int p = owr * Hh + owc + r;
      ab[((size_t)((p >> 7) * 12 + k0)) * 5120 + (p & 127) * 40 + kk] = f2bf(oacc[n][r] * inv[r]);
    }
  }
}

extern "C" void kernel_launch(void* const* d_in, const int* in_sizes, int n_in,
                              void* d_out, int out_size, void* d_ws, size_t ws_size,
                              hipStream_t stream) {
  const float* x      = (const float*)d_in[0];
  const float* w_qkv  = (const float*)d_in[1];
  const float* b_qkv  = (const float*)d_in[2];
  const float* w_proj = (const float*)d_in[3];
  const float* b_proj = (const float*)d_in[4];

  char* ws = (char*)d_ws;
  // qk 38,535,168 | vtp 24,379,392 | xTt/aoutT 24,576,000 | wqt 1,105,920 | wpt 368,640
  // total 88,965,120 B
  short* qk  = (short*)ws;
  short* vtp = (short*)(ws + 38535168);
  short* xTt = (short*)(ws + 38535168 + 24379392);
  short* wqt = (short*)(ws + 38535168 + 24379392 + 24576000);
  short* wpt = (short*)(ws + 38535168 + 24379392 + 24576000 + 1105920);

  prep_weights<<<512, 256, 0, stream>>>(w_qkv, w_proj, wqt, wpt);
  hipMemsetAsync(vtp, 0, 24379392, stream);     // zero-pad borders for V image
  transpose_x<<<8 * 100, 256, 0, stream>>>(x, xTt);
  gemm_bf16<0><<<8 * 225, 256, 0, stream>>>(wqt, xTt, b_qkv, qk, vtp);
  attn_mfma<<<8 * 294, 256, 0, stream>>>(qk, vtp, xTt);   // xTt reused as aoutT
  gemm_bf16<1><<<8 * 75, 256, 0, stream>>>(wpt, xTt, b_proj, d_out, nullptr);
}